// Round 5
// baseline (287.640 us; speedup 1.0000x reference)
//
#include <hip/hip_runtime.h>
#include <hip/hip_bf16.h>

typedef _Float16 f16;
typedef f16 f16x8 __attribute__((ext_vector_type(8)));
typedef f16 f16x4 __attribute__((ext_vector_type(4)));
typedef float f32x4 __attribute__((ext_vector_type(4)));

#define IN_F 256
#define OUT_F 128
#define BK 64
// S layout: 8 feature-slabs of 16 features: S[(slab*N + node)*16 + f]
// slab = 3.2 MB -> resident in one XCD's 4 MiB L2 (pass = blockIdx & 7)

// ---------------- W transpose + fp16 convert: Wt[n][k] = W[k][n] ----------------
__global__ __launch_bounds__(256) void prep_w(const float* __restrict__ W,
                                              f16* __restrict__ Wt) {
    int i = blockIdx.x * 256 + threadIdx.x;   // i over 256*128
    int k = i >> 7;          // row of W (0..255)
    int n = i & 127;         // col of W (0..127)
    Wt[n * IN_F + k] = (f16)W[i];
}

// ---------------- segment bounds from sorted edge_dst ----------------
__global__ __launch_bounds__(256) void seg_bounds(const int* __restrict__ dst,
                                                  int* __restrict__ rs,
                                                  int* __restrict__ re, int E) {
    int i = blockIdx.x * 256 + threadIdx.x;
    if (i >= E) return;
    int d = dst[i];
    if (i == 0 || dst[i - 1] != d) rs[d] = i;
    if (i == E - 1 || dst[i + 1] != d) re[d] = i + 1;
}

// ---------------- GEMM: S = X @ W (fp16 MFMA), slab-layout epilogue ----------------
__global__ __launch_bounds__(256) void gemm_xw(const float* __restrict__ X,
                                               const f16* __restrict__ Wt,
                                               f16* __restrict__ S, int M) {
    __shared__ f16 sx[2][128 * BK] __attribute__((aligned(16)));  // 2 x 16 KB

    const int w   = threadIdx.x >> 6;
    const int l   = threadIdx.x & 63;
    const int r   = l & 15;
    const int khi = l >> 4;
    const int wm = w >> 1, wn = w & 1;
    const int brow  = blockIdx.x * 128;
    const int mbase = wm * 64;
    const int nbase = wn * 64;

    const int srow = w * 32 + (l >> 4);   // staging row (+ j*4)
    const int scol = (l & 15) * 4;

    f32x4 acc[4][4] = {};
    float4 xv[8];

    // ---- prologue: stage K-step 0 into buf 0 ----
    #pragma unroll
    for (int j = 0; j < 8; ++j) {
        int rloc = srow + j * 4;
        int rg = brow + rloc; rg = rg < M ? rg : M - 1;
        xv[j] = *(const float4*)(X + (size_t)rg * IN_F + scol);
    }
    #pragma unroll
    for (int j = 0; j < 8; ++j) {
        int rloc = srow + j * 4;
        f16x4 hv = { (f16)xv[j].x, (f16)xv[j].y, (f16)xv[j].z, (f16)xv[j].w };
        *(f16x4*)&sx[0][rloc * BK + (scol ^ ((rloc & 7) << 3))] = hv;
    }
    __syncthreads();

    #pragma unroll
    for (int t = 0; t < 4; ++t) {
        if (t < 3) {                       // issue next K-step's loads early (T14)
            const int k0 = (t + 1) * BK;
            #pragma unroll
            for (int j = 0; j < 8; ++j) {
                int rloc = srow + j * 4;
                int rg = brow + rloc; rg = rg < M ? rg : M - 1;
                xv[j] = *(const float4*)(X + (size_t)rg * IN_F + k0 + scol);
            }
        }
        #pragma unroll
        for (int kk = 0; kk < 2; ++kk) {
            f16x8 a[4], b[4];
            const int sidx = (kk * 32 + khi * 8) ^ ((r & 7) << 3);
            #pragma unroll
            for (int m = 0; m < 4; ++m) {
                int arow = mbase + m * 16 + r;
                a[m] = *(const f16x8*)&sx[t & 1][arow * BK + sidx];
            }
            const int kg = t * BK + kk * 32 + khi * 8;
            #pragma unroll
            for (int n = 0; n < 4; ++n)
                b[n] = *(const f16x8*)(Wt + (size_t)(nbase + n * 16 + r) * IN_F + kg);
            #pragma unroll
            for (int m = 0; m < 4; ++m)
                #pragma unroll
                for (int n = 0; n < 4; ++n)
                    acc[m][n] = __builtin_amdgcn_mfma_f32_16x16x32_f16(a[m], b[n], acc[m][n], 0, 0, 0);
        }
        if (t < 3) {                       // write-late into other buffer
            #pragma unroll
            for (int j = 0; j < 8; ++j) {
                int rloc = srow + j * 4;
                f16x4 hv = { (f16)xv[j].x, (f16)xv[j].y, (f16)xv[j].z, (f16)xv[j].w };
                *(f16x4*)&sx[(t + 1) & 1][rloc * BK + (scol ^ ((rloc & 7) << 3))] = hv;
            }
        }
        __syncthreads();
    }

    // ---- epilogue: C/D D[(l>>4)*4 + i][l&15]; store into slab layout ----
    #pragma unroll
    for (int m = 0; m < 4; ++m) {
        int row0 = brow + mbase + m * 16 + khi * 4;
        #pragma unroll
        for (int i = 0; i < 4; ++i) {
            int row = row0 + i;
            if (row < M) {
                #pragma unroll
                for (int n = 0; n < 4; ++n) {
                    int slab = (nbase >> 4) + n;
                    S[((size_t)slab * M + row) * 16 + r] = (f16)acc[m][n][i];
                }
            }
        }
    }
}

// ---------------- aggregation: out[d] = tanh(bias + sum_e val[e]*S[src[e]]) ----------------
// 8 feature-slab passes; pass = blockIdx & 7 -> one slab per XCD (L2-resident).
// Half-wave (32 lanes) per node: 16 edge-slots x 2 lanes; lane covers 8 of the
// slab's 16 features via one f16x8 (16 B) gather. Edge metadata nontemporal
// (streamed, don't evict slab). Tail branch-free: clamp index, zero weight.
__global__ __launch_bounds__(256) void aggregate(const f16* __restrict__ S,
                                                 const int* __restrict__ rs,
                                                 const int* __restrict__ re,
                                                 const int* __restrict__ esrc,
                                                 const float* __restrict__ eval,
                                                 const float* __restrict__ bias,
                                                 float* __restrict__ out, int N) {
    const int pass = blockIdx.x & 7;
    const int node = (blockIdx.x >> 3) * 8 + (threadIdx.x >> 5);
    if (node >= N) return;

    const int hl   = threadIdx.x & 31;
    const int slot = hl >> 1;     // 16 edge slots
    const int half = hl & 1;      // which 8 features of the 16-slab

    const int s = rs[node];
    const int e = re[node];

    const f16* Sp = S + (size_t)pass * N * 16 + half * 8;

    float acc[8] = {};

    for (int base = s; base < e; base += 16) {
        int ei  = base + slot;
        int eic = min(ei, e - 1);
        int   se = __builtin_nontemporal_load(esrc + eic);
        float ve = __builtin_nontemporal_load(eval + eic);
        if (ei >= e) ve = 0.f;
        f16x8 h = *(const f16x8*)(Sp + (size_t)se * 16);
        #pragma unroll
        for (int q = 0; q < 8; ++q)
            acc[q] += ve * (float)h[q];
    }

    // fold 16 edge slots (offsets 2..16 stay within the 32-lane half-wave)
    #pragma unroll
    for (int q = 0; q < 8; ++q) {
        acc[q] += __shfl_xor(acc[q], 2);
        acc[q] += __shfl_xor(acc[q], 4);
        acc[q] += __shfl_xor(acc[q], 8);
        acc[q] += __shfl_xor(acc[q], 16);
    }

    if (hl < 2) {   // lane 0: features pass*16..+7, lane 1: +8..+15
        const int f0 = pass * 16 + half * 8;
        float4 b0 = *(const float4*)(bias + f0);
        float4 b1 = *(const float4*)(bias + f0 + 4);
        float4 o0, o1;
        o0.x = tanhf(acc[0] + b0.x); o0.y = tanhf(acc[1] + b0.y);
        o0.z = tanhf(acc[2] + b0.z); o0.w = tanhf(acc[3] + b0.w);
        o1.x = tanhf(acc[4] + b1.x); o1.y = tanhf(acc[5] + b1.y);
        o1.z = tanhf(acc[6] + b1.z); o1.w = tanhf(acc[7] + b1.w);
        float* op = out + (size_t)node * OUT_F + f0;
        *(float4*)op = o0;
        *(float4*)(op + 4) = o1;
    }
}

extern "C" void kernel_launch(void* const* d_in, const int* in_sizes, int n_in,
                              void* d_out, int out_size, void* d_ws, size_t ws_size,
                              hipStream_t stream) {
    const float* X    = (const float*)d_in[0];
    const float* W    = (const float*)d_in[1];
    const float* bias = (const float*)d_in[2];
    const int*   esrc = (const int*)d_in[3];
    const int*   edst = (const int*)d_in[4];
    const float* eval = (const float*)d_in[5];
    float* out = (float*)d_out;

    const int N = in_sizes[0] / IN_F;      // 100000
    const int E = in_sizes[3];             // 1600000

    // workspace layout
    char* ws = (char*)d_ws;
    f16* Wt = (f16*)ws;                                   // 128*256*2 = 64 KB
    f16* S  = (f16*)(ws + 65536);                         // 8 slabs * N * 16 * 2 = 25.6 MB
    int* rs = (int*)(ws + 65536 + (size_t)N * OUT_F * 2); // N ints
    int* re = rs + N;

    hipMemsetAsync(rs, 0, 2 * (size_t)N * sizeof(int), stream);
    prep_w<<<(IN_F * OUT_F) / 256, 256, 0, stream>>>(W, Wt);
    seg_bounds<<<(E + 255) / 256, 256, 0, stream>>>(edst, rs, re, E);
    gemm_xw<<<(N + 127) / 128, 256, 0, stream>>>(X, Wt, S, N);
    const int ngroups = (N + 7) / 8;
    aggregate<<<ngroups * 8, 256, 0, stream>>>(S, rs, re, esrc, eval, bias, out, N);
}

// Round 6
// 164.027 us; speedup vs baseline: 1.7536x; 1.7536x over previous
//
#include <hip/hip_runtime.h>
#include <hip/hip_bf16.h>

typedef _Float16 f16;
typedef f16 f16x8 __attribute__((ext_vector_type(8)));
typedef f16 f16x4 __attribute__((ext_vector_type(4)));
typedef float f32x4 __attribute__((ext_vector_type(4)));

#define IN_F 256
#define OUT_F 128
#define BK 64
// S layout: 2 feature-halves of 64: S[(h*N + node)*64 + f]  (128 B rows)
// half h is processed only by blocks with (blockIdx&1)==h -> XCD parity
// affinity (XCD = blockIdx%8): each half-row fetched by <=4 XCDs.

// ---------------- W transpose + fp16 convert: Wt[n][k] = W[k][n] ----------------
__global__ __launch_bounds__(256) void prep_w(const float* __restrict__ W,
                                              f16* __restrict__ Wt) {
    int i = blockIdx.x * 256 + threadIdx.x;   // i over 256*128
    int k = i >> 7;          // row of W (0..255)
    int n = i & 127;         // col of W (0..127)
    Wt[n * IN_F + k] = (f16)W[i];
}

// ---------------- segment bounds from sorted edge_dst ----------------
__global__ __launch_bounds__(256) void seg_bounds(const int* __restrict__ dst,
                                                  int* __restrict__ rs,
                                                  int* __restrict__ re, int E) {
    int i = blockIdx.x * 256 + threadIdx.x;
    if (i >= E) return;
    int d = dst[i];
    if (i == 0 || dst[i - 1] != d) rs[d] = i;
    if (i == E - 1 || dst[i + 1] != d) re[d] = i + 1;
}

// ---------------- GEMM: S = X @ W (fp16 MFMA), half-split epilogue ----------------
__global__ __launch_bounds__(256) void gemm_xw(const float* __restrict__ X,
                                               const f16* __restrict__ Wt,
                                               f16* __restrict__ S, int M) {
    __shared__ f16 sx[2][128 * BK] __attribute__((aligned(16)));  // 2 x 16 KB

    const int w   = threadIdx.x >> 6;
    const int l   = threadIdx.x & 63;
    const int r   = l & 15;
    const int khi = l >> 4;
    const int wm = w >> 1, wn = w & 1;
    const int brow  = blockIdx.x * 128;
    const int mbase = wm * 64;
    const int nbase = wn * 64;

    const int srow = w * 32 + (l >> 4);   // staging row (+ j*4)
    const int scol = (l & 15) * 4;

    f32x4 acc[4][4] = {};
    float4 xv[8];

    // ---- prologue: stage K-step 0 into buf 0 ----
    #pragma unroll
    for (int j = 0; j < 8; ++j) {
        int rloc = srow + j * 4;
        int rg = brow + rloc; rg = rg < M ? rg : M - 1;
        xv[j] = *(const float4*)(X + (size_t)rg * IN_F + scol);
    }
    #pragma unroll
    for (int j = 0; j < 8; ++j) {
        int rloc = srow + j * 4;
        f16x4 hv = { (f16)xv[j].x, (f16)xv[j].y, (f16)xv[j].z, (f16)xv[j].w };
        *(f16x4*)&sx[0][rloc * BK + (scol ^ ((rloc & 7) << 3))] = hv;
    }
    __syncthreads();

    #pragma unroll
    for (int t = 0; t < 4; ++t) {
        if (t < 3) {                       // issue next K-step's loads early (T14)
            const int k0 = (t + 1) * BK;
            #pragma unroll
            for (int j = 0; j < 8; ++j) {
                int rloc = srow + j * 4;
                int rg = brow + rloc; rg = rg < M ? rg : M - 1;
                xv[j] = *(const float4*)(X + (size_t)rg * IN_F + k0 + scol);
            }
        }
        #pragma unroll
        for (int kk = 0; kk < 2; ++kk) {
            f16x8 a[4], b[4];
            const int sidx = (kk * 32 + khi * 8) ^ ((r & 7) << 3);
            #pragma unroll
            for (int m = 0; m < 4; ++m) {
                int arow = mbase + m * 16 + r;
                a[m] = *(const f16x8*)&sx[t & 1][arow * BK + sidx];
            }
            const int kg = t * BK + kk * 32 + khi * 8;
            #pragma unroll
            for (int n = 0; n < 4; ++n)
                b[n] = *(const f16x8*)(Wt + (size_t)(nbase + n * 16 + r) * IN_F + kg);
            #pragma unroll
            for (int m = 0; m < 4; ++m)
                #pragma unroll
                for (int n = 0; n < 4; ++n)
                    acc[m][n] = __builtin_amdgcn_mfma_f32_16x16x32_f16(a[m], b[n], acc[m][n], 0, 0, 0);
        }
        if (t < 3) {                       // write-late into other buffer
            #pragma unroll
            for (int j = 0; j < 8; ++j) {
                int rloc = srow + j * 4;
                f16x4 hv = { (f16)xv[j].x, (f16)xv[j].y, (f16)xv[j].z, (f16)xv[j].w };
                *(f16x4*)&sx[(t + 1) & 1][rloc * BK + (scol ^ ((rloc & 7) << 3))] = hv;
            }
        }
        __syncthreads();
    }

    // ---- epilogue: C/D D[(l>>4)*4 + i][l&15]; store into half-split layout ----
    #pragma unroll
    for (int m = 0; m < 4; ++m) {
        int row0 = brow + mbase + m * 16 + khi * 4;
        #pragma unroll
        for (int i = 0; i < 4; ++i) {
            int row = row0 + i;
            if (row < M) {
                #pragma unroll
                for (int n = 0; n < 4; ++n) {
                    int col = nbase + n * 16 + r;          // 0..127
                    int hh  = col >> 6;
                    S[((size_t)hh * M + row) * 64 + (col & 63)] = (f16)acc[m][n][i];
                }
            }
        }
    }
}

// ---------------- aggregation: out[d] = tanh(bias + sum_e val[e]*S[src[e]]) ----------------
// Two XCD-affine passes: h = blockIdx&1 (XCD = blockIdx%8, so half 0 runs on
// XCDs {0,2,4,6} only). One wave per node per half: lane = (g,p), g=edge slot
// (8 edges in flight), p = 8-feature slice; gather = f16x8 (16 B) x 8 lanes =
// one 128 B line per edge. Fold g with 3 shfl_xor rounds. Tail branch-free.
__global__ __launch_bounds__(256) void aggregate(const f16* __restrict__ S,
                                                 const int* __restrict__ rs,
                                                 const int* __restrict__ re,
                                                 const int* __restrict__ esrc,
                                                 const float* __restrict__ eval,
                                                 const float* __restrict__ bias,
                                                 float* __restrict__ out, int N) {
    const int h    = blockIdx.x & 1;
    const int node = (blockIdx.x >> 1) * 4 + (threadIdx.x >> 6);
    if (node >= N) return;

    const int lane = threadIdx.x & 63;
    const int g = lane >> 3;      // edge slot 0..7
    const int p = lane & 7;       // feature slice: feats [8p, 8p+8) of the half

    const int s = rs[node];
    const int e = re[node];

    const f16* Sp = S + (size_t)h * N * 64 + p * 8;

    float acc[8] = {};

    for (int base = s; base < e; base += 8) {
        int ei  = base + g;
        int eic = min(ei, e - 1);
        int   se = esrc[eic];
        float ve = eval[eic];
        if (ei >= e) ve = 0.f;
        f16x8 hv = *(const f16x8*)(Sp + (size_t)se * 64);
        #pragma unroll
        for (int q = 0; q < 8; ++q)
            acc[q] += ve * (float)hv[q];
    }

    // fold the 8 edge slots (g = lane bits 3..5)
    #pragma unroll
    for (int q = 0; q < 8; ++q) {
        acc[q] += __shfl_xor(acc[q], 8);
        acc[q] += __shfl_xor(acc[q], 16);
        acc[q] += __shfl_xor(acc[q], 32);
    }

    if (g == 0) {   // lane p writes features h*64 + [8p, 8p+8)
        const int f0 = h * 64 + p * 8;
        float4 b0 = *(const float4*)(bias + f0);
        float4 b1 = *(const float4*)(bias + f0 + 4);
        float4 o0, o1;
        o0.x = tanhf(acc[0] + b0.x); o0.y = tanhf(acc[1] + b0.y);
        o0.z = tanhf(acc[2] + b0.z); o0.w = tanhf(acc[3] + b0.w);
        o1.x = tanhf(acc[4] + b1.x); o1.y = tanhf(acc[5] + b1.y);
        o1.z = tanhf(acc[6] + b1.z); o1.w = tanhf(acc[7] + b1.w);
        float* op = out + (size_t)node * OUT_F + f0;
        *(float4*)op = o0;
        *(float4*)(op + 4) = o1;
    }
}

extern "C" void kernel_launch(void* const* d_in, const int* in_sizes, int n_in,
                              void* d_out, int out_size, void* d_ws, size_t ws_size,
                              hipStream_t stream) {
    const float* X    = (const float*)d_in[0];
    const float* W    = (const float*)d_in[1];
    const float* bias = (const float*)d_in[2];
    const int*   esrc = (const int*)d_in[3];
    const int*   edst = (const int*)d_in[4];
    const float* eval = (const float*)d_in[5];
    float* out = (float*)d_out;

    const int N = in_sizes[0] / IN_F;      // 100000
    const int E = in_sizes[3];             // 1600000

    // workspace layout
    char* ws = (char*)d_ws;
    f16* Wt = (f16*)ws;                                   // 128*256*2 = 64 KB
    f16* S  = (f16*)(ws + 65536);                         // 2 halves * N * 64 * 2 = 25.6 MB
    int* rs = (int*)(ws + 65536 + (size_t)N * OUT_F * 2); // N ints
    int* re = rs + N;

    hipMemsetAsync(rs, 0, 2 * (size_t)N * sizeof(int), stream);
    prep_w<<<(IN_F * OUT_F) / 256, 256, 0, stream>>>(W, Wt);
    seg_bounds<<<(E + 255) / 256, 256, 0, stream>>>(edst, rs, re, E);
    gemm_xw<<<(N + 127) / 128, 256, 0, stream>>>(X, Wt, S, N);
    aggregate<<<((N + 3) / 4) * 2, 256, 0, stream>>>(S, rs, re, esrc, eval, bias, out, N);
}

// Round 7
// 116.276 us; speedup vs baseline: 2.4738x; 1.4107x over previous
//
#include <hip/hip_runtime.h>
#include <hip/hip_bf16.h>

typedef _Float16 f16;
typedef f16 f16x8 __attribute__((ext_vector_type(8)));
typedef f16 f16x4 __attribute__((ext_vector_type(4)));
typedef float f32x4 __attribute__((ext_vector_type(4)));

#define IN_F 256
#define OUT_F 128
#define BK 64
#define BM 64
// S layout: contiguous S[node][128] (f16, 256 B rows) — aggregate-optimal.

// ---------------- W transpose + fp16 convert: Wt[n][k] = W[k][n] ----------------
__global__ __launch_bounds__(256) void prep_w(const float* __restrict__ W,
                                              f16* __restrict__ Wt) {
    int i = blockIdx.x * 256 + threadIdx.x;   // i over 256*128
    int k = i >> 7;          // row of W (0..255)
    int n = i & 127;         // col of W (0..127)
    Wt[n * IN_F + k] = (f16)W[i];
}

// ---------------- segment bounds from sorted edge_dst ----------------
__global__ __launch_bounds__(256) void seg_bounds(const int* __restrict__ dst,
                                                  int* __restrict__ rs,
                                                  int* __restrict__ re, int E) {
    int i = blockIdx.x * 256 + threadIdx.x;
    if (i >= E) return;
    int d = dst[i];
    if (i == 0 || dst[i - 1] != d) rs[d] = i;
    if (i == E - 1 || dst[i + 1] != d) re[d] = i + 1;
}

// ---------------- GEMM: S = X @ W (fp16 MFMA) ----------------
// BM=64 tile (1564 blocks -> 6.1/CU, tail quantum +15% vs +31% at BM=128).
// 4 waves 2x2, wave tile 32x64. X: f16 LDS double-buffer with XOR swizzle,
// T14 issue-early/write-late. B (Wt): register double-buffer -- next K-step's
// fragments prefetched from L2 during current MFMA group.
__global__ __launch_bounds__(256) void gemm_xw(const float* __restrict__ X,
                                               const f16* __restrict__ Wt,
                                               f16* __restrict__ S, int M) {
    __shared__ f16 sx[2][BM * BK] __attribute__((aligned(16)));  // 2 x 8 KB

    const int w   = threadIdx.x >> 6;
    const int l   = threadIdx.x & 63;
    const int r   = l & 15;
    const int khi = l >> 4;
    const int wm = w >> 1, wn = w & 1;
    const int brow  = blockIdx.x * BM;
    const int mbase = wm * 32;
    const int nbase = wn * 64;

    // staging: wave w owns tile rows [w*16, w*16+16); lane covers 4 f32 cols
    const int srow = w * 16 + (l >> 4);   // + j*4
    const int scol = (l & 15) * 4;

    f32x4 acc[2][4] = {};
    float4 xv[4];
    f16x8 bcur[4], bnxt[4];

    // ---- prologue: stage K-step 0 into buf 0; load B for (t=0,kk=0) ----
    #pragma unroll
    for (int j = 0; j < 4; ++j) {
        int rloc = srow + j * 4;
        int rg = brow + rloc; rg = rg < M ? rg : M - 1;
        xv[j] = *(const float4*)(X + (size_t)rg * IN_F + scol);
    }
    #pragma unroll
    for (int n = 0; n < 4; ++n)
        bcur[n] = *(const f16x8*)(Wt + (size_t)(nbase + n * 16 + r) * IN_F + khi * 8);
    #pragma unroll
    for (int j = 0; j < 4; ++j) {
        int rloc = srow + j * 4;
        f16x4 hv = { (f16)xv[j].x, (f16)xv[j].y, (f16)xv[j].z, (f16)xv[j].w };
        *(f16x4*)&sx[0][rloc * BK + (scol ^ ((rloc & 7) << 3))] = hv;
    }
    __syncthreads();

    #pragma unroll
    for (int t = 0; t < 4; ++t) {
        if (t < 3) {                       // issue next K-step's X loads early (T14)
            const int k0 = (t + 1) * BK;
            #pragma unroll
            for (int j = 0; j < 4; ++j) {
                int rloc = srow + j * 4;
                int rg = brow + rloc; rg = rg < M ? rg : M - 1;
                xv[j] = *(const float4*)(X + (size_t)rg * IN_F + k0 + scol);
            }
        }
        #pragma unroll
        for (int kk = 0; kk < 2; ++kk) {
            // prefetch B for the next (t,kk) into the other register buffer
            const int nk = t * 2 + kk + 1;           // next group index (of 8)
            if (nk < 8) {
                const int kg = (nk >> 1) * BK + (nk & 1) * 32 + khi * 8;
                #pragma unroll
                for (int n = 0; n < 4; ++n)
                    bnxt[n] = *(const f16x8*)(Wt + (size_t)(nbase + n * 16 + r) * IN_F + kg);
            }
            f16x8 a[2];
            const int sidx = (kk * 32 + khi * 8) ^ ((r & 7) << 3);
            #pragma unroll
            for (int m = 0; m < 2; ++m) {
                int arow = mbase + m * 16 + r;
                a[m] = *(const f16x8*)&sx[t & 1][arow * BK + sidx];
            }
            #pragma unroll
            for (int m = 0; m < 2; ++m)
                #pragma unroll
                for (int n = 0; n < 4; ++n)
                    acc[m][n] = __builtin_amdgcn_mfma_f32_16x16x32_f16(a[m], bcur[n], acc[m][n], 0, 0, 0);
            #pragma unroll
            for (int n = 0; n < 4; ++n) bcur[n] = bnxt[n];
        }
        if (t < 3) {                       // write-late into other buffer
            #pragma unroll
            for (int j = 0; j < 4; ++j) {
                int rloc = srow + j * 4;
                f16x4 hv = { (f16)xv[j].x, (f16)xv[j].y, (f16)xv[j].z, (f16)xv[j].w };
                *(f16x4*)&sx[(t + 1) & 1][rloc * BK + (scol ^ ((rloc & 7) << 3))] = hv;
            }
        }
        __syncthreads();
    }

    // ---- epilogue: C/D layout D[(l>>4)*4 + i][l&15] ----
    #pragma unroll
    for (int m = 0; m < 2; ++m) {
        int row0 = brow + mbase + m * 16 + khi * 4;
        #pragma unroll
        for (int i = 0; i < 4; ++i) {
            int row = row0 + i;
            if (row < M) {
                #pragma unroll
                for (int n = 0; n < 4; ++n)
                    S[(size_t)row * OUT_F + nbase + n * 16 + r] = (f16)acc[m][n][i];
            }
        }
    }
}

// ---------------- aggregation: out[d] = tanh(bias + sum_e val[e]*S[src[e]]) ----------------
// (R4 version restored -- at the ~1 line/cy/XCD fill wall: 186 MB / 73 us.)
// One wave per node. g = lane>>4: edge slot (4 in flight), p = lane&15: 16 B
// feature slice; 16 lanes x 16 B = one 256 B row per edge.
__global__ __launch_bounds__(256) void aggregate(const f16* __restrict__ S,
                                                 const int* __restrict__ rs,
                                                 const int* __restrict__ re,
                                                 const int* __restrict__ esrc,
                                                 const float* __restrict__ eval,
                                                 const float* __restrict__ bias,
                                                 float* __restrict__ out, int N) {
    const int wave = threadIdx.x >> 6;
    const int lane = threadIdx.x & 63;
    const int node = blockIdx.x * 4 + wave;
    if (node >= N) return;

    const int g = lane >> 4;
    const int p = lane & 15;

    const int s = rs[node];
    const int e = re[node];

    float acc[8] = {};

    for (int base = s; base < e; base += 16) {
        int   se[4];
        float ve[4];
        #pragma unroll
        for (int j = 0; j < 4; ++j) {
            int ei  = base + j * 4 + g;
            int eic = min(ei, e - 1);
            se[j] = esrc[eic];
            ve[j] = eval[eic];
            if (ei >= e) ve[j] = 0.f;
        }
        f16x8 h[4];
        #pragma unroll
        for (int j = 0; j < 4; ++j)
            h[j] = *(const f16x8*)(S + (size_t)se[j] * OUT_F + p * 8);
        #pragma unroll
        for (int j = 0; j < 4; ++j)
            #pragma unroll
            for (int q = 0; q < 8; ++q)
                acc[q] += ve[j] * (float)h[j][q];
    }

    #pragma unroll
    for (int q = 0; q < 8; ++q) {
        acc[q] += __shfl_xor(acc[q], 16);
        acc[q] += __shfl_xor(acc[q], 32);
    }

    if (lane < 32) {
        const int half = lane >> 4;   // 0 or 1
        const int f0 = 8 * p + 4 * half;
        float4 bb = *(const float4*)(bias + f0);
        float4 o;
        o.x = tanhf(acc[4 * half + 0] + bb.x);
        o.y = tanhf(acc[4 * half + 1] + bb.y);
        o.z = tanhf(acc[4 * half + 2] + bb.z);
        o.w = tanhf(acc[4 * half + 3] + bb.w);
        *(float4*)(out + (size_t)node * OUT_F + f0) = o;
    }
}

extern "C" void kernel_launch(void* const* d_in, const int* in_sizes, int n_in,
                              void* d_out, int out_size, void* d_ws, size_t ws_size,
                              hipStream_t stream) {
    const float* X    = (const float*)d_in[0];
    const float* W    = (const float*)d_in[1];
    const float* bias = (const float*)d_in[2];
    const int*   esrc = (const int*)d_in[3];
    const int*   edst = (const int*)d_in[4];
    const float* eval = (const float*)d_in[5];
    float* out = (float*)d_out;

    const int N = in_sizes[0] / IN_F;      // 100000
    const int E = in_sizes[3];             // 1600000

    // workspace layout
    char* ws = (char*)d_ws;
    f16* Wt = (f16*)ws;                                   // 128*256*2 = 64 KB
    f16* S  = (f16*)(ws + 65536);                         // N*128*2 = 25.6 MB
    int* rs = (int*)(ws + 65536 + (size_t)N * OUT_F * 2); // N ints
    int* re = rs + N;

    hipMemsetAsync(rs, 0, 2 * (size_t)N * sizeof(int), stream);
    prep_w<<<(IN_F * OUT_F) / 256, 256, 0, stream>>>(W, Wt);
    seg_bounds<<<(E + 255) / 256, 256, 0, stream>>>(edst, rs, re, E);
    gemm_xw<<<(N + BM - 1) / BM, 256, 0, stream>>>(X, Wt, S, N);
    aggregate<<<(N + 3) / 4, 256, 0, stream>>>(S, rs, re, esrc, eval, bias, out, N);
}

// Round 8
// 109.705 us; speedup vs baseline: 2.6219x; 1.0599x over previous
//
#include <hip/hip_runtime.h>
#include <hip/hip_bf16.h>

typedef _Float16 f16;
typedef f16 f16x8 __attribute__((ext_vector_type(8)));
typedef f16 f16x4 __attribute__((ext_vector_type(4)));
typedef float f32x4 __attribute__((ext_vector_type(4)));

#define IN_F 256
#define OUT_F 128
#define BM 64

// ---------------- fused prep: Wt transpose + segment bounds (no memset) ----------------
// i < 32768:  Wt[n][k] = (f16)W[k][n]
// i < E:      rs/re from sorted dst, with gap-fill so every node is written
//             (expected gap work ~ N*e^-16 ~ 0; replaces the memset kernel).
__global__ __launch_bounds__(256) void prep(const float* __restrict__ W,
                                            f16* __restrict__ Wt,
                                            const int* __restrict__ dst,
                                            int* __restrict__ rs,
                                            int* __restrict__ re,
                                            int E, int N) {
    int i = blockIdx.x * 256 + threadIdx.x;
    if (i < IN_F * OUT_F) {
        int k = i >> 7;          // row of W (0..255)
        int n = i & 127;         // col of W (0..127)
        Wt[n * IN_F + k] = (f16)W[i];
    }
    if (i < E) {
        int d = dst[i];
        if (i == 0) {
            rs[d] = 0;
            for (int v = 0; v < d; ++v) { rs[v] = 0; re[v] = 0; }
        } else {
            int a = dst[i - 1];
            if (a != d) {
                re[a] = i;
                rs[d] = i;
                for (int v = a + 1; v < d; ++v) { rs[v] = i; re[v] = i; }
            }
        }
        if (i == E - 1) {
            re[d] = E;
            for (int v = d + 1; v < N; ++v) { rs[v] = E; re[v] = E; }
        }
    }
}

// ---------------- GEMM: S = X @ W (fp16 MFMA), single-K-shot ----------------
// BM=64, BK=256 (full K). Whole 64x256 X tile staged once: 16 float4 global
// loads per thread in flight (deep issue), f32->f16 cvt, XOR-swizzled f16 LDS
// tile (32 KB), ONE barrier, then 8 MFMA groups x 8 MFMA with B register
// double-buffer from L2-hot Wt. 4 blocks/CU co-resident smooth the HBM pipe.
__global__ __launch_bounds__(256, 4) void gemm_xw(const float* __restrict__ X,
                                                  const f16* __restrict__ Wt,
                                                  f16* __restrict__ S, int M) {
    __shared__ f16 sx[BM * IN_F] __attribute__((aligned(16)));   // 64x256 f16 = 32 KB

    const int w   = threadIdx.x >> 6;
    const int l   = threadIdx.x & 63;
    const int r   = l & 15;
    const int khi = l >> 4;
    const int wm = w >> 1, wn = w & 1;
    const int brow  = blockIdx.x * BM;
    const int mbase = wm * 32;
    const int nbase = wn * 64;

    f32x4 acc[2][4] = {};
    f16x8 bcur[4], bnxt[4];

    // B prefetch for MFMA group 0 (overlaps the X staging burst)
    #pragma unroll
    for (int n = 0; n < 4; ++n)
        bcur[n] = *(const f16x8*)(Wt + (size_t)(nbase + n * 16 + r) * IN_F + khi * 8);

    // ---- stage the whole 64x256 X tile as swizzled f16 ----
    // instr (jr,jc): row = w*16 + jr*4 + (l>>4), colf32 = jc*64 + (l&15)*4
    #pragma unroll
    for (int jr = 0; jr < 4; ++jr) {
        const int rloc = w * 16 + jr * 4 + (l >> 4);
        int rg = brow + rloc; rg = rg < M ? rg : M - 1;
        const float* xp = X + (size_t)rg * IN_F + (l & 15) * 4;
        float4 xv[4];
        #pragma unroll
        for (int jc = 0; jc < 4; ++jc)
            xv[jc] = *(const float4*)(xp + jc * 64);
        #pragma unroll
        for (int jc = 0; jc < 4; ++jc) {
            f16x4 hv = { (f16)xv[jc].x, (f16)xv[jc].y, (f16)xv[jc].z, (f16)xv[jc].w };
            const int cf16 = (jc * 64 + (l & 15) * 4) ^ ((rloc & 15) << 3);
            *(f16x4*)&sx[rloc * IN_F + cf16] = hv;
        }
    }
    __syncthreads();

    // ---- 8 MFMA groups over K=256 ----
    #pragma unroll
    for (int kk = 0; kk < 8; ++kk) {
        if (kk < 7) {                      // prefetch next group's B fragments
            const int kg = (kk + 1) * 32 + khi * 8;
            #pragma unroll
            for (int n = 0; n < 4; ++n)
                bnxt[n] = *(const f16x8*)(Wt + (size_t)(nbase + n * 16 + r) * IN_F + kg);
        }
        f16x8 a[2];
        #pragma unroll
        for (int m = 0; m < 2; ++m) {
            const int arow = mbase + m * 16 + r;          // arow & 15 == r
            const int cf16 = (kk * 32 + khi * 8) ^ (r << 3);
            a[m] = *(const f16x8*)&sx[arow * IN_F + cf16];
        }
        #pragma unroll
        for (int m = 0; m < 2; ++m)
            #pragma unroll
            for (int n = 0; n < 4; ++n)
                acc[m][n] = __builtin_amdgcn_mfma_f32_16x16x32_f16(a[m], bcur[n], acc[m][n], 0, 0, 0);
        #pragma unroll
        for (int n = 0; n < 4; ++n) bcur[n] = bnxt[n];
    }

    // ---- epilogue: C/D layout D[(l>>4)*4 + i][l&15] ----
    #pragma unroll
    for (int m = 0; m < 2; ++m) {
        int row0 = brow + mbase + m * 16 + khi * 4;
        #pragma unroll
        for (int i = 0; i < 4; ++i) {
            int row = row0 + i;
            if (row < M) {
                #pragma unroll
                for (int n = 0; n < 4; ++n)
                    S[(size_t)row * OUT_F + nbase + n * 16 + r] = (f16)acc[m][n][i];
            }
        }
    }
}

// ---------------- aggregation: out[d] = tanh(bias + sum_e val[e]*S[src[e]]) ----------------
// (R4 version -- at the ~1 line/cy/XCD beyond-L2 fill wall: 186 MB / 73 us.)
// One wave per node. g = lane>>4: edge slot (4 in flight), p = lane&15: 16 B
// feature slice; 16 lanes x 16 B = one 256 B row per edge.
__global__ __launch_bounds__(256) void aggregate(const f16* __restrict__ S,
                                                 const int* __restrict__ rs,
                                                 const int* __restrict__ re,
                                                 const int* __restrict__ esrc,
                                                 const float* __restrict__ eval,
                                                 const float* __restrict__ bias,
                                                 float* __restrict__ out, int N) {
    const int wave = threadIdx.x >> 6;
    const int lane = threadIdx.x & 63;
    const int node = blockIdx.x * 4 + wave;
    if (node >= N) return;

    const int g = lane >> 4;
    const int p = lane & 15;

    const int s = rs[node];
    const int e = re[node];

    float acc[8] = {};

    for (int base = s; base < e; base += 16) {
        int   se[4];
        float ve[4];
        #pragma unroll
        for (int j = 0; j < 4; ++j) {
            int ei  = base + j * 4 + g;
            int eic = min(ei, e - 1);
            se[j] = esrc[eic];
            ve[j] = eval[eic];
            if (ei >= e) ve[j] = 0.f;
        }
        f16x8 h[4];
        #pragma unroll
        for (int j = 0; j < 4; ++j)
            h[j] = *(const f16x8*)(S + (size_t)se[j] * OUT_F + p * 8);
        #pragma unroll
        for (int j = 0; j < 4; ++j)
            #pragma unroll
            for (int q = 0; q < 8; ++q)
                acc[q] += ve[j] * (float)h[j][q];
    }

    #pragma unroll
    for (int q = 0; q < 8; ++q) {
        acc[q] += __shfl_xor(acc[q], 16);
        acc[q] += __shfl_xor(acc[q], 32);
    }

    if (lane < 32) {
        const int half = lane >> 4;   // 0 or 1
        const int f0 = 8 * p + 4 * half;
        float4 bb = *(const float4*)(bias + f0);
        float4 o;
        o.x = tanhf(acc[4 * half + 0] + bb.x);
        o.y = tanhf(acc[4 * half + 1] + bb.y);
        o.z = tanhf(acc[4 * half + 2] + bb.z);
        o.w = tanhf(acc[4 * half + 3] + bb.w);
        *(float4*)(out + (size_t)node * OUT_F + f0) = o;
    }
}

extern "C" void kernel_launch(void* const* d_in, const int* in_sizes, int n_in,
                              void* d_out, int out_size, void* d_ws, size_t ws_size,
                              hipStream_t stream) {
    const float* X    = (const float*)d_in[0];
    const float* W    = (const float*)d_in[1];
    const float* bias = (const float*)d_in[2];
    const int*   esrc = (const int*)d_in[3];
    const int*   edst = (const int*)d_in[4];
    const float* eval = (const float*)d_in[5];
    float* out = (float*)d_out;

    const int N = in_sizes[0] / IN_F;      // 100000
    const int E = in_sizes[3];             // 1600000

    // workspace layout
    char* ws = (char*)d_ws;
    f16* Wt = (f16*)ws;                                   // 128*256*2 = 64 KB
    f16* S  = (f16*)(ws + 65536);                         // N*128*2 = 25.6 MB
    int* rs = (int*)(ws + 65536 + (size_t)N * OUT_F * 2); // N ints
    int* re = rs + N;

    prep<<<(E + 255) / 256, 256, 0, stream>>>(W, Wt, edst, rs, re, E, N);
    gemm_xw<<<(N + BM - 1) / BM, 256, 0, stream>>>(X, Wt, S, N);
    aggregate<<<(N + 3) / 4, 256, 0, stream>>>(S, rs, re, esrc, eval, bias, out, N);
}